// Round 12
// baseline (273.405 us; speedup 1.0000x reference)
//
#include <hip/hip_runtime.h>
#include <cstdint>

typedef unsigned short u16;
typedef _Float16 half8 __attribute__((ext_vector_type(8)));
typedef float floatx4 __attribute__((ext_vector_type(4)));
typedef unsigned short ushort8v __attribute__((ext_vector_type(8)));
typedef unsigned short ushort4v __attribute__((ext_vector_type(4)));
typedef float float4v __attribute__((ext_vector_type(4)));

#define BB 2048
#define UU 1024
#define HUx 256
#define O_H  0
#define O_C  (BB*UU)
#define O_HO (2*BB*UU)
#define O_HC (2*BB*UU + BB*HUx)
#define MFMAH __builtin_amdgcn_mfma_f32_16x16x32_f16

// raw barrier: ds-write visibility (lgkmcnt) without the __syncthreads vmcnt(0) drain,
// so prefetched global loads stay in flight across barriers (T3/T4 mechanism).
// sched_barrier(0) pins ordering (rule #18: hipcc can hoist reg-only ops past asm waitcnt).
#define LBAR() do { \
    asm volatile("s_waitcnt lgkmcnt(0)\n\ts_barrier" ::: "memory"); \
    __builtin_amdgcn_sched_barrier(0); \
} while (0)

__device__ __forceinline__ float bf2f(u16 u) {
    union { uint32_t i; float f; } v; v.i = ((uint32_t)u) << 16; return v.f;
}
__device__ __forceinline__ u16 f2bf(float f) {
    union { float f; uint32_t i; } v; v.f = f;
    uint32_t r = v.i + 0x7fffu + ((v.i >> 16) & 1u);
    return (u16)(r >> 16);
}
__device__ __forceinline__ u16 f2h(float f) {
    _Float16 h = (_Float16)f; u16 u; __builtin_memcpy(&u, &h, 2); return u;
}
__device__ __forceinline__ float sigf(float x) { return 1.f / (1.f + expf(-x)); }
__device__ __forceinline__ float ldmix(const void* p, size_t i, int isbf) {
    return isbf ? bf2f(((const u16*)p)[i]) : ((const float*)p)[i];
}
// load input element (bf16 or fp32) -> fp16 bits
__device__ __forceinline__ u16 ld2h(const void* p, size_t i, int isbf) {
    return f2h(ldmix(p, i, isbf));
}

// split staging: load-to-regs / write-to-LDS (prefetch pipeline; 256-thread blocks)
__device__ __forceinline__ void ld128(half8 r[2], const u16* src, int row0, int ldK,
                                      int k0, int tid) {
    #pragma unroll
    for (int i = 0; i < 2; i++) {
        int v = tid + 256 * i;
        r[i] = *(const half8*)(src + (size_t)(row0 + (v >> 2)) * ldK + k0 + (v & 3) * 8);
    }
}
__device__ __forceinline__ void ld64(half8& r, const u16* src, int row0, int ldK,
                                     int k0, int tid) {
    r = *(const half8*)(src + (size_t)(row0 + (tid >> 2)) * ldK + k0 + (tid & 3) * 8);
}
// ---- r8: unpadded 64B-row + XOR-swizzle layout (conflict-free reads AND writes) ----
// row stride 32 u16 = 4 bank-quads; phys slot = slot ^ ((row>>1)&3).
// PROVEN r8: SQ_LDS_BANK_CONFLICT 1.52e7 -> 0.
__device__ __forceinline__ void wrS128(u16* lds, const half8 r[2], int tid) {
    #pragma unroll
    for (int i = 0; i < 2; i++) {
        int v = tid + 256 * i;
        int ps = (v & 3) ^ ((v >> 3) & 3);
        *(half8*)&lds[(v >> 2) * 32 + ps * 8] = r[i];
    }
}
__device__ __forceinline__ void wrS64(u16* lds, half8 r, int tid) {
    int ps = (tid & 3) ^ ((tid >> 3) & 3);
    *(half8*)&lds[(tid >> 2) * 32 + ps * 8] = r;
}

// ---------------- per-block dtype detect (1 = bf16, 0 = fp32) ----------------
__device__ __forceinline__ int detect_local(const u16* raw) {
    int lane = threadIdx.x & 63;
    u16 u = raw[2 * lane];
    int e = (u >> 7) & 0xFF;
    unsigned long long m = __ballot(e >= 100 && e <= 134);
    return (__popcll(m) >= 32) ? 1 : 0;
}

// ---------------- vectorized 32x32 transpose+convert tile (r10-proven) ----------------
__device__ __forceinline__ void transpose_tile_v(const void* in, u16* out, int C,
                                                 int ostride, int ocol, int r0, int c0,
                                                 int isbf, u16* th /*[32*36]*/) {
    int tid = threadIdx.x;
    int ty = tid >> 3, tx4 = (tid & 7) * 4;
    ushort4v v;
    if (isbf) {
        ushort4v q = *(const ushort4v*)((const u16*)in + (size_t)(r0 + ty) * C + c0 + tx4);
        #pragma unroll
        for (int j = 0; j < 4; j++) v[j] = f2h(bf2f(q[j]));
    } else {
        float4v q = *(const float4v*)((const float*)in + (size_t)(r0 + ty) * C + c0 + tx4);
        #pragma unroll
        for (int j = 0; j < 4; j++) v[j] = f2h(q[j]);
    }
    *(ushort4v*)&th[ty * 36 + tx4] = v;
    __syncthreads();
    ushort4v w;
    #pragma unroll
    for (int j = 0; j < 4; j++) w[j] = th[(tx4 + j) * 36 + ty];
    *(ushort4v*)(out + (size_t)(c0 + ty) * ostride + ocol + r0 + tx4) = w;
}

// ---------------- prep_in: dtype-detect + input cvt + hyper-weight (BTh) transpose ----------------
// 4608 blocks: [0,2304) cvt, [2304,4352) hyper_k, [4352,4608) hyper_rk. (r10-proven)
__global__ __launch_bounds__(256) void prep_in(
    const void* __restrict__ xs, const void* __restrict__ ms, const void* __restrict__ hs,
    const void* __restrict__ hyper_k, const void* __restrict__ hyper_rk,
    u16* __restrict__ xh, u16* __restrict__ mh, u16* __restrict__ hh,
    u16* __restrict__ BTh, int* __restrict__ flag) {
    __shared__ __align__(16) u16 th[32 * 36];
    int bid = blockIdx.x, tid = threadIdx.x;
    int isbf = detect_local((const u16*)xs);
    if (bid == 0 && tid == 0) *flag = isbf;

    if (bid < 2304) {
        int i = bid * 256 + tid;
        const void* src; u16* dst; int t;
        if (i < 262144)      { src = xs; dst = xh; t = i; }
        else if (i < 524288) { src = ms; dst = mh; t = i - 262144; }
        else                 { src = hs; dst = hh; t = i - 524288; }  // < 589824
        half8 o;
        if (isbf) {
            ushort8v v = *(const ushort8v*)((const u16*)src + (size_t)t * 8);
            #pragma unroll
            for (int j = 0; j < 8; j++) o[j] = (_Float16)bf2f(v[j]);
        } else {
            float4v a = *(const float4v*)((const float*)src + (size_t)t * 8);
            float4v b = *(const float4v*)((const float*)src + (size_t)t * 8 + 4);
            #pragma unroll
            for (int j = 0; j < 4; j++) { o[j] = (_Float16)a[j]; o[j + 4] = (_Float16)b[j]; }
        }
        *(half8*)(dst + (size_t)t * 8) = o;
    } else if (bid < 4352) {
        int u = bid - 2304;
        transpose_tile_v(hyper_k, BTh, 1024, 2304, 0, (u >> 5) * 32, (u & 31) * 32, isbf, th);
    } else {
        int u = bid - 4352;
        transpose_tile_v(hyper_rk, BTh, 1024, 2304, 2048, (u >> 5) * 32, (u & 31) * 32, isbf, th);
    }
}

// ---------------- hyper GEMM + LSTM cell fused, wave-split-K (r12) + transposes ----------------
// r11 post-mortem: fused cell was right, parallelism was wrong (128 blocks x 72 steps,
// 0.5/CU -> ~2x gemm critical path). r12: block = 128 rows x 64 gate-cols, 4 waves =
// 2(M) x 2(K-half). Each K-half runs 36 steps over its 1152-K slice with its OWN
// double-buffered LDS set (lockstep LBAR, equal barrier counts). wk=1 dumps acc to LDS
// (reused staging space); wk=0 adds + runs the in-register cell. 256 gemm blocks (r10
// parallelism restored) + 11264 transpose blocks co-resident.
// tn INDEXES THE GATE: B-row br in [0,64): gate=br>>4, hu=br&15; BT col = gate*256 +
// sx*16 + hu. fp32 partial sums added in fp32 == r10 split-K numerics.
__global__ __launch_bounds__(256) void gemm_cell_wt(
    const u16* __restrict__ xh, const u16* __restrict__ mh, const u16* __restrict__ hh,
    const u16* __restrict__ BT,
    const void* __restrict__ xs, const void* __restrict__ hyper_c,
    const void* __restrict__ hyper_b, void* __restrict__ out, u16* __restrict__ ho16,
    const void* __restrict__ kernel_w, const void* __restrict__ rec_w,
    const void* __restrict__ dx_w, const void* __restrict__ dh_w,
    const void* __restrict__ db_w,
    u16* __restrict__ kT, u16* __restrict__ rkT,
    u16* __restrict__ dxT, u16* __restrict__ dhT, u16* __restrict__ dbT) {
    // per half h, per buf p: A@0 (128x32 = 4096 u16), B@4096 (64x32 = 2048 u16)
    __shared__ __align__(16) u16 S[2][2][6144];  // 48 KB
    int bid = blockIdx.x, tid = threadIdx.x;

    if (bid >= 256) {
        // ---- weight-transpose role (r10-proven) ----
        int isbf = detect_local((const u16*)xs);
        int u = bid - 256;
        const void* in; u16* outT; int ostride, r0, c0;
        if (u < 8192) {
            in  = (u < 4096) ? kernel_w : rec_w;
            outT = (u < 4096) ? kT : rkT;
            int r = u & 4095;
            ostride = 1024; r0 = (r >> 7) * 32; c0 = (r & 127) * 32;
        } else {
            int v = u - 8192;
            int zi = v >> 10, r = v & 1023;
            in  = (zi == 0) ? dx_w : (zi == 1) ? dh_w : db_w;
            outT = (zi == 0) ? dxT : (zi == 1) ? dhT : dbT;
            ostride = 256; r0 = (r >> 7) * 32; c0 = (r & 127) * 32;
        }
        transpose_tile_v(in, outT, 4096, ostride, 0, r0, c0, isbf, (u16*)S);
        return;
    }

    // ---- gemm+cell role ----
    int isbf = detect_local((const u16*)xs);
    int lane = tid & 63, wave = tid >> 6;
    int wm = (wave & 1) * 64, wk = wave >> 1;     // wk = K-half
    int t128 = tid & 127;                          // half-local staging index
    int sx = bid & 15, by = bid >> 4;              // sx: 16-hu strip, by: M tile
    int bm = by * 128;
    int mr = lane & 15;
    int kqs = ((lane >> 4) ^ ((mr >> 1) & 3)) * 8; // r8-proven swizzled read offset
    int sBase = wk * 36;                           // this half's step range
    floatx4 acc[4][4] = {};

    half8 nA[4], nB[2];

    // half-local loaders: A = 128x32 (4 vec8/thread), B = 64x32 (2 vec8/thread)
    #define LDA_H(R, S_) do { \
        int s_ = (S_); \
        const u16* Ap_; int ldA_, kA_; \
        if (s_ < 32)      { Ap_ = xh; ldA_ = 1024; kA_ = s_ * 32; } \
        else if (s_ < 64) { Ap_ = mh; ldA_ = 1024; kA_ = (s_ - 32) * 32; } \
        else              { Ap_ = hh; ldA_ = 256;  kA_ = (s_ - 64) * 32; } \
        _Pragma("unroll") \
        for (int i_ = 0; i_ < 4; i_++) { \
            int v_ = t128 + 128 * i_; \
            (R)[i_] = *(const half8*)(Ap_ + (size_t)(bm + (v_ >> 2)) * ldA_ + kA_ + (v_ & 3) * 8); \
        } \
    } while (0)
    #define LDB_H(R, S_) do { \
        int s_ = (S_); \
        _Pragma("unroll") \
        for (int i_ = 0; i_ < 2; i_++) { \
            int v_ = t128 + 128 * i_; \
            int br_ = v_ >> 2; \
            int col_ = (br_ >> 4) * 256 + sx * 16 + (br_ & 15); \
            (R)[i_] = *(const half8*)(BT + (size_t)col_ * 2304 + s_ * 32 + (v_ & 3) * 8); \
        } \
    } while (0)
    #define WRA_H(L, R) do { \
        _Pragma("unroll") \
        for (int i_ = 0; i_ < 4; i_++) { \
            int v_ = t128 + 128 * i_; \
            int ps_ = (v_ & 3) ^ ((v_ >> 3) & 3); \
            *(half8*)&(L)[(v_ >> 2) * 32 + ps_ * 8] = (R)[i_]; \
        } \
    } while (0)
    #define WRB_H(L, R) do { \
        _Pragma("unroll") \
        for (int i_ = 0; i_ < 2; i_++) { \
            int v_ = t128 + 128 * i_; \
            int ps_ = (v_ & 3) ^ ((v_ >> 3) & 3); \
            *(half8*)&(L)[4096 + (v_ >> 2) * 32 + ps_ * 8] = (R)[i_]; \
        } \
    } while (0)

    // prologue: tile0 (this half) -> regs -> buf0; tile1 -> regs; barrier
    LDA_H(nA, sBase); LDB_H(nB, sBase);
    WRA_H(S[wk][0], nA); WRB_H(S[wk][0], nB);
    LDA_H(nA, sBase + 1); LDB_H(nB, sBase + 1);
    LBAR();

    #pragma unroll 1
    for (int j = 0; j < 36; j++) {
        int p = j & 1;
        const u16* C = S[wk][p];
        u16* N = S[wk][p ^ 1];
        half8 a[4], b[4];
        #pragma unroll
        for (int t = 0; t < 4; t++)
            a[t] = *(const half8*)&C[(wm + t * 16 + mr) * 32 + kqs];
        #pragma unroll
        for (int t = 0; t < 4; t++)
            b[t] = *(const half8*)&C[4096 + (t * 16 + mr) * 32 + kqs];
        if (j < 35) {
            WRA_H(N, nA); WRB_H(N, nB);
            if (j < 34) { LDA_H(nA, sBase + j + 2); LDB_H(nB, sBase + j + 2); }
        }
        #pragma unroll
        for (int tm = 0; tm < 4; tm++)
            #pragma unroll
            for (int tn = 0; tn < 4; tn++)
                acc[tm][tn] = MFMAH(a[tm], b[tn], acc[tm][tn], 0, 0, 0);
        LBAR();
    }
    #undef LDA_H
    #undef LDB_H
    #undef WRA_H
    #undef WRB_H

    // ---- cross-half reduction (reuse staging LDS as float scratch, 32 KB) ----
    float* red = (float*)S;
    if (wk == 1) {
        int t = tid - 128;
        #pragma unroll
        for (int tm = 0; tm < 4; tm++)
            #pragma unroll
            for (int tn = 0; tn < 4; tn++)
                *(floatx4*)&red[t * 64 + (tm * 4 + tn) * 4] = acc[tm][tn];
    }
    __syncthreads();
    if (wk == 0) {
        #pragma unroll
        for (int tm = 0; tm < 4; tm++)
            #pragma unroll
            for (int tn = 0; tn < 4; tn++)
                acc[tm][tn] += *(const floatx4*)&red[tid * 64 + (tm * 4 + tn) * 4];

        // in-register LSTM cell. tn = gate (i,f,g,o); hu = sx*16 + mr.
        int hu = sx * 16 + mr;
        float bi = ldmix(hyper_b, hu, isbf);
        float bf = ldmix(hyper_b, hu + 256, isbf);
        float bg = ldmix(hyper_b, hu + 512, isbf);
        float bo = ldmix(hyper_b, hu + 768, isbf);
        #pragma unroll
        for (int tm = 0; tm < 4; tm++) {
            #pragma unroll
            for (int rr = 0; rr < 4; rr++) {
                int row = bm + wm + tm * 16 + (lane >> 4) * 4 + rr;
                size_t idx = (size_t)row * 256 + hu;
                float hi = acc[tm][0][rr] + bi;
                float hf = acc[tm][1][rr] + bf;
                float hg = acc[tm][2][rr] + bg;
                float hoo = acc[tm][3][rr] + bo;
                float c = ldmix(hyper_c, idx, isbf);
                float cn = sigf(hf) * c + sigf(hi) * tanhf(hg);
                float hout = sigf(hoo) * tanhf(cn);
                ho16[idx] = f2h(hout);
                if (isbf) {
                    ((u16*)out)[O_HO + idx] = f2bf(hout);
                    ((u16*)out)[O_HC + idx] = f2bf(cn);
                } else {
                    ((float*)out)[O_HO + idx] = hout;
                    ((float*)out)[O_HC + idx] = cn;
                }
            }
        }
    }
}

// ---------------- fused gates GEMM (fp16, 5 acc sets) -> gates_pre fp16 ----------------
// block 128M x 64N, waves 2(M)x2(N), wave tile 64x32 PER SET.
// r7: LDS double-buffer, 1 LBAR/step, reg-prefetch dist 1 (87.8us).
// r8: XOR-swizzle layout -> bank conflicts 1.52e7 -> 0; 80.3us, MfmaUtil 24.8%.
// UNCHANGED since r8.
__global__ __launch_bounds__(256, 2) void mega_fused(
    const u16* __restrict__ xh, const u16* __restrict__ mh, const u16* __restrict__ ho16,
    const u16* __restrict__ kT, const u16* __restrict__ rkT,
    const u16* __restrict__ dxT, const u16* __restrict__ dhT, const u16* __restrict__ dbT,
    const void* __restrict__ bias, const void* __restrict__ dx_b,
    const void* __restrict__ dh_b, const void* __restrict__ db_b,
    u16* __restrict__ gp, const int* __restrict__ flag) {
    __shared__ __align__(16) u16 S[2][12288];
    int isbf = *flag;
    int tid = threadIdx.x, lane = tid & 63, wave = tid >> 6;
    int wm = (wave & 1) * 64, wn = (wave >> 1) * 32;
    int bm = blockIdx.y * 128, bn = blockIdx.x * 64;
    floatx4 apx[4][2] = {}, aph[4][2] = {}, adx[4][2] = {}, adh[4][2] = {}, adb[4][2] = {};
    int mr = lane & 15;
    // swizzled k-chunk offset: phys slot = (lane>>4) ^ ((row>>1)&3); row>>1&3 == mr>>1&3
    // (wm/wn/t*16 are multiples of 16 -> contribute 0). Same involution as wrS*.
    int kqs = (((lane >> 4) ^ ((mr >> 1) & 3))) * 8;

    half8 nA1[2], nA2[2], nB1, nB2, nB3;

    // ---- prologue: tile0 -> regs -> buf0 ; tile1 -> regs ; barrier ----
    ld128(nA1, xh,  bm, 1024, 0, tid);
    ld128(nA2, mh,  bm, 1024, 0, tid);
    ld64(nB1, kT,  bn, 1024, 0, tid);
    ld64(nB2, rkT, bn, 1024, 0, tid);
    wrS128(S[0], nA1, tid); wrS128(S[0] + 4096, nA2, tid);
    wrS64(S[0] + 8192, nB1, tid); wrS64(S[0] + 10240, nB2, tid);
    ld128(nA1, xh,  bm, 1024, 32, tid);
    ld128(nA2, mh,  bm, 1024, 32, tid);
    ld64(nB1, kT,  bn, 1024, 32, tid);
    ld64(nB2, rkT, bn, 1024, 32, tid);
    LBAR();

    // ---- phase 1: px = x@kT, ph = mh@rkT  (K=1024), 1 barrier/step ----
    #pragma unroll 1
    for (int k0 = 0; k0 < 1024; k0 += 32) {
        int p = (k0 >> 5) & 1;
        const u16* C = S[p];
        u16* N = S[p ^ 1];
        half8 ax[4], am[4], bk[2], br[2];
        #pragma unroll
        for (int t = 0; t < 4; t++) {
            int ra = (wm + t * 16 + mr) * 32 + kqs;
            ax[t] = *(const half8*)&C[ra];
            am[t] = *(const half8*)&C[4096 + ra];
        }
        #pragma unroll
        for (int t = 0; t < 2; t++) {
            int rb = (wn + t * 16 + mr) * 32 + kqs;
            bk[t] = *(const half8*)&C[8192 + rb];
            br[t] = *(const half8*)&C[10240 + rb];
        }
        // stage next tile (in regs) into the other buffer — overlaps MFMA below
        if (k0 < 992) {
            wrS128(N, nA1, tid); wrS128(N + 4096, nA2, tid);
            wrS64(N + 8192, nB1, tid); wrS64(N + 10240, nB2, tid);
        } else {
            // last ph1 step: stage PHASE-2 tile0 (loaded at k0==960), phase2 layout
            wrS128(N, nA1, tid);
            wrS64(N + 8192, nB1, tid); wrS64(N + 10240, nB2, tid); wrS64(N + 4096, nB3, tid);
        }
        // prefetch tile k0+64 into regs
        if (k0 < 960) {
            ld128(nA1, xh,  bm, 1024, k0 + 64, tid);
            ld128(nA2, mh,  bm, 1024, k0 + 64, tid);
            ld64(nB1, kT,  bn, 1024, k0 + 64, tid);
            ld64(nB2, rkT, bn, 1024, k0 + 64, tid);
        } else if (k0 == 960) {
            ld128(nA1, ho16, bm, 256, 0, tid);
            ld64(nB1, dxT, bn, 256, 0, tid);
            ld64(nB2, dhT, bn, 256, 0, tid);
            ld64(nB3, dbT, bn, 256, 0, tid);
        } else {  // k0 == 992: phase-2 tile1
            ld128(nA1, ho16, bm, 256, 32, tid);
            ld64(nB1, dxT, bn, 256, 32, tid);
            ld64(nB2, dhT, bn, 256, 32, tid);
            ld64(nB3, dbT, bn, 256, 32, tid);
        }
        #pragma unroll
        for (int tm = 0; tm < 4; tm++)
            #pragma unroll
            for (int tn = 0; tn < 2; tn++) {
                apx[tm][tn] = MFMAH(ax[tm], bk[tn], apx[tm][tn], 0, 0, 0);
                aph[tm][tn] = MFMAH(am[tm], br[tn], aph[tm][tn], 0, 0, 0);
            }
        LBAR();
    }

    // ---- phase 2: d_* = ho @ {dxT,dhT,dbT}  (K=256); A shared by 3 sets ----
    #pragma unroll 1
    for (int k0 = 0; k0 < 256; k0 += 32) {
        int p = (k0 >> 5) & 1;
        const u16* C = S[p];
        u16* N = S[p ^ 1];
        half8 a[4], bx[2], bh[2], bb[2];
        #pragma unroll
        for (int t = 0; t < 4; t++) {
            int ra = (wm + t * 16 + mr) * 32 + kqs;
            a[t] = *(const half8*)&C[ra];
        }
        #pragma unroll
        for (int t = 0; t < 2; t++) {
            int rb = (wn + t * 16 + mr) * 32 + kqs;
            bx[t] = *(const half8*)&C[8192 + rb];
            bh[t] = *(const half8*)&C[10240 + rb];
            bb[t] = *(const half8*)&C[4096 + rb];
        }
        if (k0 < 224) {
            wrS128(N, nA1, tid);
            wrS64(N + 8192, nB1, tid); wrS64(N + 10240, nB2, tid); wrS64(N + 4096, nB3, tid);
        }
        if (k0 < 192) {
            ld128(nA1, ho16, bm, 256, k0 + 64, tid);
            ld64(nB1, dxT, bn, 256, k0 + 64, tid);
            ld64(nB2, dhT, bn, 256, k0 + 64, tid);
            ld64(nB3, dbT, bn, 256, k0 + 64, tid);
        }
        #pragma unroll
        for (int tm = 0; tm < 4; tm++)
            #pragma unroll
            for (int tn = 0; tn < 2; tn++) {
                adx[tm][tn] = MFMAH(a[tm], bx[tn], adx[tm][tn], 0, 0, 0);
                adh[tm][tn] = MFMAH(a[tm], bh[tn], adh[tm][tn], 0, 0, 0);
                adb[tm][tn] = MFMAH(a[tm], bb[tn], adb[tm][tn], 0, 0, 0);
            }
        LBAR();
    }

    // epilogue: g = (adx+dxb)*(apx+bias) + (adh+dhb)*aph + (adb+dbb), stored fp16
    #pragma unroll
    for (int tn = 0; tn < 2; tn++) {
        int col = bn + wn + tn * 16 + (lane & 15);
        float bv  = ldmix(bias, col, isbf);
        float dxb = ldmix(dx_b, col, isbf);
        float dhb = ldmix(dh_b, col, isbf);
        float dbb = ldmix(db_b, col, isbf);
        #pragma unroll
        for (int tm = 0; tm < 4; tm++) {
            #pragma unroll
            for (int rr = 0; rr < 4; rr++) {
                int row = bm + wm + tm * 16 + (lane >> 4) * 4 + rr;
                float px = apx[tm][tn][rr] + bv;
                float ph = aph[tm][tn][rr];
                float dx = adx[tm][tn][rr] + dxb;
                float dh = adh[tm][tn][rr] + dhb;
                float db = adb[tm][tn][rr] + dbb;
                gp[(size_t)row * 4096 + col] = f2h(dx * px + dh * ph + db);
            }
        }
    }
}

// ---------------- LN(4096) -> gates -> c_new -> LN(1024) -> h_new ----------------
__device__ __forceinline__ void block_reduce2(float& a, float& b, float* red) {
    #pragma unroll
    for (int o = 32; o > 0; o >>= 1) {
        a += __shfl_down(a, o, 64);
        b += __shfl_down(b, o, 64);
    }
    int lane = threadIdx.x & 63, w = threadIdx.x >> 6;
    if (lane == 0) { red[w] = a; red[4 + w] = b; }
    __syncthreads();
    a = red[0] + red[1] + red[2] + red[3];
    b = red[4] + red[5] + red[6] + red[7];
    __syncthreads();
}

__global__ __launch_bounds__(256) void ln_main(const u16* __restrict__ gp,
                                               const void* __restrict__ main_c,
                                               void* __restrict__ out,
                                               const int* __restrict__ flag) {
    __shared__ float sPre[4096];
    __shared__ float sC[1024];
    __shared__ float red[8];
    int isbf = *flag;
    int b = blockIdx.x, tid = threadIdx.x;
    const u16* g = gp + (size_t)b * 4096;
    float s = 0.f, q = 0.f;
    for (int j0 = tid * 8; j0 < 4096; j0 += 2048) {
        half8 v = *(const half8*)(g + j0);
        #pragma unroll
        for (int e = 0; e < 8; e++) {
            float f = (float)v[e];
            sPre[j0 + e] = f; s += f; q += f * f;
        }
    }
    block_reduce2(s, q, red);
    float mean = s * (1.f / 4096.f);
    float var = q * (1.f / 4096.f) - mean * mean;
    float rs = rsqrtf(var + 1e-3f);
    float s2 = 0.f, q2 = 0.f;
    for (int u = tid; u < 1024; u += 256) {
        float gi = (sPre[u] - mean) * rs;
        float gf = (sPre[u + 1024] - mean) * rs;
        float gg = (sPre[u + 2048] - mean) * rs;
        float c = ldmix(main_c, (size_t)b * 1024 + u, isbf);
        float cn = sigf(gf) * c + sigf(gi) * tanhf(gg);
        sC[u] = cn;
        if (isbf) ((u16*)out)[O_C + (size_t)b * 1024 + u] = f2bf(cn);
        else      ((float*)out)[O_C + (size_t)b * 1024 + u] = cn;
        s2 += cn; q2 += cn * cn;
    }
    block_reduce2(s2, q2, red);
    float m2 = s2 * (1.f / 1024.f);
    float v2 = q2 * (1.f / 1024.f) - m2 * m2;
    float rs2 = rsqrtf(v2 + 1e-3f);
    for (int u = tid; u < 1024; u += 256) {
        float go = (sPre[u + 3072] - mean) * rs;
        float hn = sigf(go) * tanhf((sC[u] - m2) * rs2);
        if (isbf) ((u16*)out)[O_H + (size_t)b * 1024 + u] = f2bf(hn);
        else      ((float*)out)[O_H + (size_t)b * 1024 + u] = hn;
    }
}

// ---------------- launcher ----------------
extern "C" void kernel_launch(void* const* d_in, const int* in_sizes, int n_in,
                              void* d_out, int out_size, void* d_ws, size_t ws_size,
                              hipStream_t stream) {
    (void)in_sizes; (void)n_in; (void)out_size; (void)ws_size;
    const void* inputs   = d_in[0];
    const void* main_h   = d_in[1];
    const void* main_c   = d_in[2];
    const void* hyper_h  = d_in[3];
    const void* hyper_c  = d_in[4];
    const void* kernel_w = d_in[5];
    const void* rec_w    = d_in[6];
    const void* bias     = d_in[7];
    const void* hyper_k  = d_in[8];
    const void* hyper_rk = d_in[9];
    const void* hyper_b  = d_in[10];
    const void* dx_w = d_in[11];
    const void* dx_b = d_in[12];
    const void* dh_w = d_in[13];
    const void* dh_b = d_in[14];
    const void* db_w = d_in[15];
    const void* db_b = d_in[16];
    char* ws = (char*)d_ws;
    const size_t MB = 1024 * 1024;

    // workspace layout, NO overlays
    int* flag = (int*)ws;
    size_t off = 256;
    u16* xh  = (u16*)(ws + off); off += 4 * MB;            // [2048,1024] fp16
    u16* mh  = (u16*)(ws + off); off += 4 * MB;            // [2048,1024] fp16
    u16* hh  = (u16*)(ws + off); off += 1 * MB;            // [2048,256]  fp16
    u16* ho  = (u16*)(ws + off); off += 1 * MB;            // [2048,256]  fp16
    u16* kT  = (u16*)(ws + off); off += 8 * MB;            // [4096,1024] fp16
    u16* rkT = (u16*)(ws + off); off += 8 * MB;            // [4096,1024] fp16
    u16* dxT = (u16*)(ws + off); off += 2 * MB;            // [4096,256]  fp16
    u16* dhT = (u16*)(ws + off); off += 2 * MB;
    u16* dbT = (u16*)(ws + off); off += 2 * MB;
    u16* BTh = (u16*)(ws + off); off += (size_t)1024 * 2304 * 2;  // 4.5 MB
    u16* gp  = (u16*)(ws + off); off += 16 * MB;           // [2048,4096] fp16

    // r12: 4 launches — fused cell kept, r10-level gemm parallelism restored.
    prep_in<<<4608, 256, 0, stream>>>(inputs, main_h, hyper_h, hyper_k, hyper_rk,
                                      xh, mh, hh, BTh, flag);
    gemm_cell_wt<<<256 + 11264, 256, 0, stream>>>(xh, mh, hh, BTh,
                                                  inputs, hyper_c, hyper_b, d_out, ho,
                                                  kernel_w, rec_w, dx_w, dh_w, db_w,
                                                  kT, rkT, dxT, dhT, dbT);
    mega_fused<<<dim3(64, 16), 256, 0, stream>>>(xh, mh, ho, kT, rkT, dxT, dhT, dbT,
                                                 bias, dx_b, dh_b, db_b, gp, flag);
    ln_main<<<2048, 256, 0, stream>>>(gp, main_c, d_out, flag);
}

// Round 13
// 257.191 us; speedup vs baseline: 1.0630x; 1.0630x over previous
//
#include <hip/hip_runtime.h>
#include <cstdint>

typedef unsigned short u16;
typedef _Float16 half8 __attribute__((ext_vector_type(8)));
typedef float floatx4 __attribute__((ext_vector_type(4)));
typedef unsigned short ushort8v __attribute__((ext_vector_type(8)));
typedef unsigned short ushort4v __attribute__((ext_vector_type(4)));
typedef float float4v __attribute__((ext_vector_type(4)));

#define BB 2048
#define UU 1024
#define HUx 256
#define O_H  0
#define O_C  (BB*UU)
#define O_HO (2*BB*UU)
#define O_HC (2*BB*UU + BB*HUx)
#define MFMAH __builtin_amdgcn_mfma_f32_16x16x32_f16

// raw barrier: ds-write visibility (lgkmcnt) without the __syncthreads vmcnt(0) drain,
// so prefetched global loads stay in flight across barriers (T3/T4 mechanism).
// sched_barrier(0) pins ordering (rule #18: hipcc can hoist reg-only ops past asm waitcnt).
#define LBAR() do { \
    asm volatile("s_waitcnt lgkmcnt(0)\n\ts_barrier" ::: "memory"); \
    __builtin_amdgcn_sched_barrier(0); \
} while (0)

__device__ __forceinline__ float bf2f(u16 u) {
    union { uint32_t i; float f; } v; v.i = ((uint32_t)u) << 16; return v.f;
}
__device__ __forceinline__ u16 f2bf(float f) {
    union { float f; uint32_t i; } v; v.f = f;
    uint32_t r = v.i + 0x7fffu + ((v.i >> 16) & 1u);
    return (u16)(r >> 16);
}
__device__ __forceinline__ u16 f2h(float f) {
    _Float16 h = (_Float16)f; u16 u; __builtin_memcpy(&u, &h, 2); return u;
}
__device__ __forceinline__ float sigf(float x) { return 1.f / (1.f + expf(-x)); }
__device__ __forceinline__ float ldmix(const void* p, size_t i, int isbf) {
    return isbf ? bf2f(((const u16*)p)[i]) : ((const float*)p)[i];
}
// load input element (bf16 or fp32) -> fp16 bits
__device__ __forceinline__ u16 ld2h(const void* p, size_t i, int isbf) {
    return f2h(ldmix(p, i, isbf));
}

// split staging: load-to-regs / write-to-LDS (prefetch pipeline; 256-thread blocks)
__device__ __forceinline__ void ld128(half8 r[2], const u16* src, int row0, int ldK,
                                      int k0, int tid) {
    #pragma unroll
    for (int i = 0; i < 2; i++) {
        int v = tid + 256 * i;
        r[i] = *(const half8*)(src + (size_t)(row0 + (v >> 2)) * ldK + k0 + (v & 3) * 8);
    }
}
__device__ __forceinline__ void ld64(half8& r, const u16* src, int row0, int ldK,
                                     int k0, int tid) {
    r = *(const half8*)(src + (size_t)(row0 + (tid >> 2)) * ldK + k0 + (tid & 3) * 8);
}
// ---- r8: unpadded 64B-row + XOR-swizzle layout (conflict-free reads AND writes) ----
// row stride 32 u16 = 4 bank-quads; phys slot = slot ^ ((row>>1)&3).
// PROVEN r8: SQ_LDS_BANK_CONFLICT 1.52e7 -> 0.
__device__ __forceinline__ void wrS128(u16* lds, const half8 r[2], int tid) {
    #pragma unroll
    for (int i = 0; i < 2; i++) {
        int v = tid + 256 * i;
        int ps = (v & 3) ^ ((v >> 3) & 3);
        *(half8*)&lds[(v >> 2) * 32 + ps * 8] = r[i];
    }
}
__device__ __forceinline__ void wrS64(u16* lds, half8 r, int tid) {
    int ps = (tid & 3) ^ ((tid >> 3) & 3);
    *(half8*)&lds[(tid >> 2) * 32 + ps * 8] = r;
}

// ---------------- per-block dtype detect (1 = bf16, 0 = fp32) ----------------
__device__ __forceinline__ int detect_local(const u16* raw) {
    int lane = threadIdx.x & 63;
    u16 u = raw[2 * lane];
    int e = (u >> 7) & 0xFF;
    unsigned long long m = __ballot(e >= 100 && e <= 134);
    return (__popcll(m) >= 32) ? 1 : 0;
}

// ---------------- vectorized 32x32 transpose+convert tile (r10-proven) ----------------
__device__ __forceinline__ void transpose_tile_v(const void* in, u16* out, int C,
                                                 int ostride, int ocol, int r0, int c0,
                                                 int isbf, u16* th /*[32*36]*/) {
    int tid = threadIdx.x;
    int ty = tid >> 3, tx4 = (tid & 7) * 4;
    ushort4v v;
    if (isbf) {
        ushort4v q = *(const ushort4v*)((const u16*)in + (size_t)(r0 + ty) * C + c0 + tx4);
        #pragma unroll
        for (int j = 0; j < 4; j++) v[j] = f2h(bf2f(q[j]));
    } else {
        float4v q = *(const float4v*)((const float*)in + (size_t)(r0 + ty) * C + c0 + tx4);
        #pragma unroll
        for (int j = 0; j < 4; j++) v[j] = f2h(q[j]);
    }
    *(ushort4v*)&th[ty * 36 + tx4] = v;
    __syncthreads();
    ushort4v w;
    #pragma unroll
    for (int j = 0; j < 4; j++) w[j] = th[(tx4 + j) * 36 + ty];
    *(ushort4v*)(out + (size_t)(c0 + ty) * ostride + ocol + r0 + tx4) = w;
}

// ---------------- prep_in: dtype-detect + input cvt + hyper-weight (BTh) transpose ----------------
// 4608 blocks: [0,2304) cvt, [2304,4352) hyper_k, [4352,4608) hyper_rk. (r10-proven)
__global__ __launch_bounds__(256) void prep_in(
    const void* __restrict__ xs, const void* __restrict__ ms, const void* __restrict__ hs,
    const void* __restrict__ hyper_k, const void* __restrict__ hyper_rk,
    u16* __restrict__ xh, u16* __restrict__ mh, u16* __restrict__ hh,
    u16* __restrict__ BTh, int* __restrict__ flag) {
    __shared__ __align__(16) u16 th[32 * 36];
    int bid = blockIdx.x, tid = threadIdx.x;
    int isbf = detect_local((const u16*)xs);
    if (bid == 0 && tid == 0) *flag = isbf;

    if (bid < 2304) {
        int i = bid * 256 + tid;
        const void* src; u16* dst; int t;
        if (i < 262144)      { src = xs; dst = xh; t = i; }
        else if (i < 524288) { src = ms; dst = mh; t = i - 262144; }
        else                 { src = hs; dst = hh; t = i - 524288; }  // < 589824
        half8 o;
        if (isbf) {
            ushort8v v = *(const ushort8v*)((const u16*)src + (size_t)t * 8);
            #pragma unroll
            for (int j = 0; j < 8; j++) o[j] = (_Float16)bf2f(v[j]);
        } else {
            float4v a = *(const float4v*)((const float*)src + (size_t)t * 8);
            float4v b = *(const float4v*)((const float*)src + (size_t)t * 8 + 4);
            #pragma unroll
            for (int j = 0; j < 4; j++) { o[j] = (_Float16)a[j]; o[j + 4] = (_Float16)b[j]; }
        }
        *(half8*)(dst + (size_t)t * 8) = o;
    } else if (bid < 4352) {
        int u = bid - 2304;
        transpose_tile_v(hyper_k, BTh, 1024, 2304, 0, (u >> 5) * 32, (u & 31) * 32, isbf, th);
    } else {
        int u = bid - 4352;
        transpose_tile_v(hyper_rk, BTh, 1024, 2304, 2048, (u >> 5) * 32, (u & 31) * 32, isbf, th);
    }
}

// ---------------- hyper GEMM fused with mega-weight transposes (r13) ----------------
// r12 post-mortem: both fused-cell variants regressed (271.4 / 273.4 vs r10 259.4)
// -> REVERTED to the r10 structure (512 gemm blocks x 36 steps + separate hyper_cell).
// r13 delta: port mega's r7/r8-proven K-loop to the gemm role — LDS double-buffer with
// ONE LBAR/step (ds_writes overlap MFMA) + unpadded stride-32 XOR-swizzle layout
// (bank conflicts -> 0). S2 = 2 x (A 128x32 @0, B 64x32 @4096) = 24 KB.
// bids [512,12288): kT/rkT/dxT/dhT/dbT transposes (r10-proven co-occupancy).
__device__ __forceinline__ void gh_load(half8 pA[2], half8& pB,
                                        const u16* xh, const u16* mh, const u16* hh,
                                        const u16* BT, int bm, int bn, int s, int tid) {
    const u16* Ap; int ldA, kA;
    if (s < 32)      { Ap = xh; ldA = 1024; kA = s * 32; }
    else if (s < 64) { Ap = mh; ldA = 1024; kA = (s - 32) * 32; }
    else             { Ap = hh; ldA = 256;  kA = (s - 64) * 32; }
    ld128(pA, Ap, bm, ldA, kA, tid);
    ld64(pB, BT, bn, 2304, s * 32, tid);
}

__global__ __launch_bounds__(256) void gemm_hyper_wt(
    const u16* __restrict__ xh, const u16* __restrict__ mh, const u16* __restrict__ hh,
    const u16* __restrict__ BT, float* __restrict__ z,
    const void* __restrict__ xs,
    const void* __restrict__ kernel_w, const void* __restrict__ rec_w,
    const void* __restrict__ dx_w, const void* __restrict__ dh_w,
    const void* __restrict__ db_w,
    u16* __restrict__ kT, u16* __restrict__ rkT,
    u16* __restrict__ dxT, u16* __restrict__ dhT, u16* __restrict__ dbT) {
    __shared__ __align__(16) u16 S2[2][6144];  // per buf: A@0 (128x32), B@4096 (64x32)
    int bid = blockIdx.x, tid = threadIdx.x;

    if (bid >= 512) {
        // ---- weight-transpose role (r10-proven) ----
        int isbf = detect_local((const u16*)xs);
        int u = bid - 512;
        const void* in; u16* out; int ostride, r0, c0;
        if (u < 8192) {
            in  = (u < 4096) ? kernel_w : rec_w;
            out = (u < 4096) ? kT : rkT;
            int r = u & 4095;
            ostride = 1024; r0 = (r >> 7) * 32; c0 = (r & 127) * 32;
        } else {
            int v = u - 8192;
            int zi = v >> 10, r = v & 1023;
            in  = (zi == 0) ? dx_w : (zi == 1) ? dh_w : db_w;
            out = (zi == 0) ? dxT : (zi == 1) ? dhT : dbT;
            ostride = 256; r0 = (r >> 7) * 32; c0 = (r & 127) * 32;
        }
        transpose_tile_v(in, out, 4096, ostride, 0, r0, c0, isbf, (u16*)S2);
        return;
    }

    // ---- gemm role: r4 geometry + r7 dbuf/1-LBAR + r8 swizzle ----
    int bxv = bid & 15, byv = (bid >> 4) & 15, bzv = bid >> 8;
    int lane = tid & 63, wave = tid >> 6;
    int wm = (wave & 1) * 64, wn = (wave >> 1) * 32;
    int bm = byv * 128, bn = bxv * 64;
    int s0 = bzv * 36, s1 = s0 + 36;
    floatx4 acc[4][2] = {};
    int mr = lane & 15;
    int kqs = ((lane >> 4) ^ ((mr >> 1) & 3)) * 8;  // r8-proven swizzled read offset

    half8 pA[2]; half8 pB;
    gh_load(pA, pB, xh, mh, hh, BT, bm, bn, s0, tid);
    wrS128(S2[0], pA, tid); wrS64(S2[0] + 4096, pB, tid);
    gh_load(pA, pB, xh, mh, hh, BT, bm, bn, s0 + 1, tid);
    LBAR();

    #pragma unroll 1
    for (int s = s0; s < s1; s++) {
        int p = (s - s0) & 1;
        const u16* C = S2[p];
        u16* N = S2[p ^ 1];
        half8 a[4], b[2];
        #pragma unroll
        for (int t = 0; t < 4; t++)
            a[t] = *(const half8*)&C[(wm + t * 16 + mr) * 32 + kqs];
        #pragma unroll
        for (int t = 0; t < 2; t++)
            b[t] = *(const half8*)&C[4096 + (wn + t * 16 + mr) * 32 + kqs];
        // stage next tile into the other buffer — overlaps MFMA below
        if (s < s1 - 1) {
            wrS128(N, pA, tid); wrS64(N + 4096, pB, tid);
            if (s < s1 - 2)
                gh_load(pA, pB, xh, mh, hh, BT, bm, bn, s + 2, tid);
        }
        #pragma unroll
        for (int tm = 0; tm < 4; tm++)
            #pragma unroll
            for (int tn = 0; tn < 2; tn++)
                acc[tm][tn] = MFMAH(a[tm], b[tn], acc[tm][tn], 0, 0, 0);
        LBAR();
    }

    float* zp = z + (size_t)bzv * 2048 * 1024;
    #pragma unroll
    for (int tm = 0; tm < 4; tm++)
        #pragma unroll
        for (int tn = 0; tn < 2; tn++) {
            int col = bn + wn + tn * 16 + (lane & 15);
            #pragma unroll
            for (int rr = 0; rr < 4; rr++) {
                int row = bm + wm + tm * 16 + (lane >> 4) * 4 + rr;
                zp[(size_t)row * 1024 + col] = acc[tm][tn][rr];
            }
        }
}

// ---------------- hyper LSTM cell (sums split-K halves); ho stored fp16 ----------------
__global__ void hyper_cell(const float* __restrict__ z, const void* __restrict__ hyper_c,
                           const void* __restrict__ hyper_bias, void* __restrict__ out,
                           u16* __restrict__ ho16, const int* __restrict__ flag) {
    int isbf = *flag;
    int t = blockIdx.x * 256 + threadIdx.x;
    int k = t & 255;
    const float* zr  = z + (size_t)(t >> 8) * 1024;
    const float* zr2 = zr + (size_t)2048 * 1024;
    float hi = zr[k]       + zr2[k]       + ldmix(hyper_bias, k, isbf);
    float hf = zr[k + 256] + zr2[k + 256] + ldmix(hyper_bias, k + 256, isbf);
    float hg = zr[k + 512] + zr2[k + 512] + ldmix(hyper_bias, k + 512, isbf);
    float ho = zr[k + 768] + zr2[k + 768] + ldmix(hyper_bias, k + 768, isbf);
    float c  = ldmix(hyper_c, t, isbf);
    float cn = sigf(hf) * c + sigf(hi) * tanhf(hg);
    float hout = sigf(ho) * tanhf(cn);
    ho16[t] = f2h(hout);
    if (isbf) {
        ((u16*)out)[O_HO + t] = f2bf(hout);
        ((u16*)out)[O_HC + t] = f2bf(cn);
    } else {
        ((float*)out)[O_HO + t] = hout;
        ((float*)out)[O_HC + t] = cn;
    }
}

// ---------------- fused gates GEMM (fp16, 5 acc sets) -> gates_pre fp16 ----------------
// block 128M x 64N, waves 2(M)x2(N), wave tile 64x32 PER SET.
// r7: LDS double-buffer, 1 LBAR/step, reg-prefetch dist 1 (87.8us).
// r8: XOR-swizzle layout -> bank conflicts 1.52e7 -> 0; 80.3us, MfmaUtil 24.8%.
// UNCHANGED since r8.
__global__ __launch_bounds__(256, 2) void mega_fused(
    const u16* __restrict__ xh, const u16* __restrict__ mh, const u16* __restrict__ ho16,
    const u16* __restrict__ kT, const u16* __restrict__ rkT,
    const u16* __restrict__ dxT, const u16* __restrict__ dhT, const u16* __restrict__ dbT,
    const void* __restrict__ bias, const void* __restrict__ dx_b,
    const void* __restrict__ dh_b, const void* __restrict__ db_b,
    u16* __restrict__ gp, const int* __restrict__ flag) {
    __shared__ __align__(16) u16 S[2][12288];
    int isbf = *flag;
    int tid = threadIdx.x, lane = tid & 63, wave = tid >> 6;
    int wm = (wave & 1) * 64, wn = (wave >> 1) * 32;
    int bm = blockIdx.y * 128, bn = blockIdx.x * 64;
    floatx4 apx[4][2] = {}, aph[4][2] = {}, adx[4][2] = {}, adh[4][2] = {}, adb[4][2] = {};
    int mr = lane & 15;
    // swizzled k-chunk offset: phys slot = (lane>>4) ^ ((row>>1)&3); row>>1&3 == mr>>1&3
    // (wm/wn/t*16 are multiples of 16 -> contribute 0). Same involution as wrS*.
    int kqs = (((lane >> 4) ^ ((mr >> 1) & 3))) * 8;

    half8 nA1[2], nA2[2], nB1, nB2, nB3;

    // ---- prologue: tile0 -> regs -> buf0 ; tile1 -> regs ; barrier ----
    ld128(nA1, xh,  bm, 1024, 0, tid);
    ld128(nA2, mh,  bm, 1024, 0, tid);
    ld64(nB1, kT,  bn, 1024, 0, tid);
    ld64(nB2, rkT, bn, 1024, 0, tid);
    wrS128(S[0], nA1, tid); wrS128(S[0] + 4096, nA2, tid);
    wrS64(S[0] + 8192, nB1, tid); wrS64(S[0] + 10240, nB2, tid);
    ld128(nA1, xh,  bm, 1024, 32, tid);
    ld128(nA2, mh,  bm, 1024, 32, tid);
    ld64(nB1, kT,  bn, 1024, 32, tid);
    ld64(nB2, rkT, bn, 1024, 32, tid);
    LBAR();

    // ---- phase 1: px = x@kT, ph = mh@rkT  (K=1024), 1 barrier/step ----
    #pragma unroll 1
    for (int k0 = 0; k0 < 1024; k0 += 32) {
        int p = (k0 >> 5) & 1;
        const u16* C = S[p];
        u16* N = S[p ^ 1];
        half8 ax[4], am[4], bk[2], br[2];
        #pragma unroll
        for (int t = 0; t < 4; t++) {
            int ra = (wm + t * 16 + mr) * 32 + kqs;
            ax[t] = *(const half8*)&C[ra];
            am[t] = *(const half8*)&C[4096 + ra];
        }
        #pragma unroll
        for (int t = 0; t < 2; t++) {
            int rb = (wn + t * 16 + mr) * 32 + kqs;
            bk[t] = *(const half8*)&C[8192 + rb];
            br[t] = *(const half8*)&C[10240 + rb];
        }
        // stage next tile (in regs) into the other buffer — overlaps MFMA below
        if (k0 < 992) {
            wrS128(N, nA1, tid); wrS128(N + 4096, nA2, tid);
            wrS64(N + 8192, nB1, tid); wrS64(N + 10240, nB2, tid);
        } else {
            // last ph1 step: stage PHASE-2 tile0 (loaded at k0==960), phase2 layout
            wrS128(N, nA1, tid);
            wrS64(N + 8192, nB1, tid); wrS64(N + 10240, nB2, tid); wrS64(N + 4096, nB3, tid);
        }
        // prefetch tile k0+64 into regs
        if (k0 < 960) {
            ld128(nA1, xh,  bm, 1024, k0 + 64, tid);
            ld128(nA2, mh,  bm, 1024, k0 + 64, tid);
            ld64(nB1, kT,  bn, 1024, k0 + 64, tid);
            ld64(nB2, rkT, bn, 1024, k0 + 64, tid);
        } else if (k0 == 960) {
            ld128(nA1, ho16, bm, 256, 0, tid);
            ld64(nB1, dxT, bn, 256, 0, tid);
            ld64(nB2, dhT, bn, 256, 0, tid);
            ld64(nB3, dbT, bn, 256, 0, tid);
        } else {  // k0 == 992: phase-2 tile1
            ld128(nA1, ho16, bm, 256, 32, tid);
            ld64(nB1, dxT, bn, 256, 32, tid);
            ld64(nB2, dhT, bn, 256, 32, tid);
            ld64(nB3, dbT, bn, 256, 32, tid);
        }
        #pragma unroll
        for (int tm = 0; tm < 4; tm++)
            #pragma unroll
            for (int tn = 0; tn < 2; tn++) {
                apx[tm][tn] = MFMAH(ax[tm], bk[tn], apx[tm][tn], 0, 0, 0);
                aph[tm][tn] = MFMAH(am[tm], br[tn], aph[tm][tn], 0, 0, 0);
            }
        LBAR();
    }

    // ---- phase 2: d_* = ho @ {dxT,dhT,dbT}  (K=256); A shared by 3 sets ----
    #pragma unroll 1
    for (int k0 = 0; k0 < 256; k0 += 32) {
        int p = (k0 >> 5) & 1;
        const u16* C = S[p];
        u16* N = S[p ^ 1];
        half8 a[4], bx[2], bh[2], bb[2];
        #pragma unroll
        for (int t = 0; t < 4; t++) {
            int ra = (wm + t * 16 + mr) * 32 + kqs;
            a[t] = *(const half8*)&C[ra];
        }
        #pragma unroll
        for (int t = 0; t < 2; t++) {
            int rb = (wn + t * 16 + mr) * 32 + kqs;
            bx[t] = *(const half8*)&C[8192 + rb];
            bh[t] = *(const half8*)&C[10240 + rb];
            bb[t] = *(const half8*)&C[4096 + rb];
        }
        if (k0 < 224) {
            wrS128(N, nA1, tid);
            wrS64(N + 8192, nB1, tid); wrS64(N + 10240, nB2, tid); wrS64(N + 4096, nB3, tid);
        }
        if (k0 < 192) {
            ld128(nA1, ho16, bm, 256, k0 + 64, tid);
            ld64(nB1, dxT, bn, 256, k0 + 64, tid);
            ld64(nB2, dhT, bn, 256, k0 + 64, tid);
            ld64(nB3, dbT, bn, 256, k0 + 64, tid);
        }
        #pragma unroll
        for (int tm = 0; tm < 4; tm++)
            #pragma unroll
            for (int tn = 0; tn < 2; tn++) {
                adx[tm][tn] = MFMAH(a[tm], bx[tn], adx[tm][tn], 0, 0, 0);
                adh[tm][tn] = MFMAH(a[tm], bh[tn], adh[tm][tn], 0, 0, 0);
                adb[tm][tn] = MFMAH(a[tm], bb[tn], adb[tm][tn], 0, 0, 0);
            }
        LBAR();
    }

    // epilogue: g = (adx+dxb)*(apx+bias) + (adh+dhb)*aph + (adb+dbb), stored fp16
    #pragma unroll
    for (int tn = 0; tn < 2; tn++) {
        int col = bn + wn + tn * 16 + (lane & 15);
        float bv  = ldmix(bias, col, isbf);
        float dxb = ldmix(dx_b, col, isbf);
        float dhb = ldmix(dh_b, col, isbf);
        float dbb = ldmix(db_b, col, isbf);
        #pragma unroll
        for (int tm = 0; tm < 4; tm++) {
            #pragma unroll
            for (int rr = 0; rr < 4; rr++) {
                int row = bm + wm + tm * 16 + (lane >> 4) * 4 + rr;
                float px = apx[tm][tn][rr] + bv;
                float ph = aph[tm][tn][rr];
                float dx = adx[tm][tn][rr] + dxb;
                float dh = adh[tm][tn][rr] + dhb;
                float db = adb[tm][tn][rr] + dbb;
                gp[(size_t)row * 4096 + col] = f2h(dx * px + dh * ph + db);
            }
        }
    }
}

// ---------------- LN(4096) -> gates -> c_new -> LN(1024) -> h_new ----------------
__device__ __forceinline__ void block_reduce2(float& a, float& b, float* red) {
    #pragma unroll
    for (int o = 32; o > 0; o >>= 1) {
        a += __shfl_down(a, o, 64);
        b += __shfl_down(b, o, 64);
    }
    int lane = threadIdx.x & 63, w = threadIdx.x >> 6;
    if (lane == 0) { red[w] = a; red[4 + w] = b; }
    __syncthreads();
    a = red[0] + red[1] + red[2] + red[3];
    b = red[4] + red[5] + red[6] + red[7];
    __syncthreads();
}

__global__ __launch_bounds__(256) void ln_main(const u16* __restrict__ gp,
                                               const void* __restrict__ main_c,
                                               void* __restrict__ out,
                                               const int* __restrict__ flag) {
    __shared__ float sPre[4096];
    __shared__ float sC[1024];
    __shared__ float red[8];
    int isbf = *flag;
    int b = blockIdx.x, tid = threadIdx.x;
    const u16* g = gp + (size_t)b * 4096;
    float s = 0.f, q = 0.f;
    for (int j0 = tid * 8; j0 < 4096; j0 += 2048) {
        half8 v = *(const half8*)(g + j0);
        #pragma unroll
        for (int e = 0; e < 8; e++) {
            float f = (float)v[e];
            sPre[j0 + e] = f; s += f; q += f * f;
        }
    }
    block_reduce2(s, q, red);
    float mean = s * (1.f / 4096.f);
    float var = q * (1.f / 4096.f) - mean * mean;
    float rs = rsqrtf(var + 1e-3f);
    float s2 = 0.f, q2 = 0.f;
    for (int u = tid; u < 1024; u += 256) {
        float gi = (sPre[u] - mean) * rs;
        float gf = (sPre[u + 1024] - mean) * rs;
        float gg = (sPre[u + 2048] - mean) * rs;
        float c = ldmix(main_c, (size_t)b * 1024 + u, isbf);
        float cn = sigf(gf) * c + sigf(gi) * tanhf(gg);
        sC[u] = cn;
        if (isbf) ((u16*)out)[O_C + (size_t)b * 1024 + u] = f2bf(cn);
        else      ((float*)out)[O_C + (size_t)b * 1024 + u] = cn;
        s2 += cn; q2 += cn * cn;
    }
    block_reduce2(s2, q2, red);
    float m2 = s2 * (1.f / 1024.f);
    float v2 = q2 * (1.f / 1024.f) - m2 * m2;
    float rs2 = rsqrtf(v2 + 1e-3f);
    for (int u = tid; u < 1024; u += 256) {
        float go = (sPre[u + 3072] - mean) * rs;
        float hn = sigf(go) * tanhf((sC[u] - m2) * rs2);
        if (isbf) ((u16*)out)[O_H + (size_t)b * 1024 + u] = f2bf(hn);
        else      ((float*)out)[O_H + (size_t)b * 1024 + u] = hn;
    }
}

// ---------------- launcher ----------------
extern "C" void kernel_launch(void* const* d_in, const int* in_sizes, int n_in,
                              void* d_out, int out_size, void* d_ws, size_t ws_size,
                              hipStream_t stream) {
    (void)in_sizes; (void)n_in; (void)out_size; (void)ws_size;
    const void* inputs   = d_in[0];
    const void* main_h   = d_in[1];
    const void* main_c   = d_in[2];
    const void* hyper_h  = d_in[3];
    const void* hyper_c  = d_in[4];
    const void* kernel_w = d_in[5];
    const void* rec_w    = d_in[6];
    const void* bias     = d_in[7];
    const void* hyper_k  = d_in[8];
    const void* hyper_rk = d_in[9];
    const void* hyper_b  = d_in[10];
    const void* dx_w = d_in[11];
    const void* dx_b = d_in[12];
    const void* dh_w = d_in[13];
    const void* dh_b = d_in[14];
    const void* db_w = d_in[15];
    const void* db_b = d_in[16];
    char* ws = (char*)d_ws;
    const size_t MB = 1024 * 1024;

    // workspace layout, NO overlays
    int* flag = (int*)ws;
    size_t off = 256;
    u16* xh  = (u16*)(ws + off); off += 4 * MB;            // [2048,1024] fp16
    u16* mh  = (u16*)(ws + off); off += 4 * MB;            // [2048,1024] fp16
    u16* hh  = (u16*)(ws + off); off += 1 * MB;            // [2048,256]  fp16
    u16* ho  = (u16*)(ws + off); off += 1 * MB;            // [2048,256]  fp16
    u16* kT  = (u16*)(ws + off); off += 8 * MB;            // [4096,1024] fp16
    u16* rkT = (u16*)(ws + off); off += 8 * MB;            // [4096,1024] fp16
    u16* dxT = (u16*)(ws + off); off += 2 * MB;            // [4096,256]  fp16
    u16* dhT = (u16*)(ws + off); off += 2 * MB;
    u16* dbT = (u16*)(ws + off); off += 2 * MB;
    u16* BTh = (u16*)(ws + off); off += (size_t)1024 * 2304 * 2;  // 4.5 MB
    float* zbuf = (float*)(ws + off); off += 16 * MB;      // [2, 2048,1024] fp32 (split-K halves)
    u16* gp  = (u16*)(ws + off); off += 16 * MB;           // [2048,4096] fp16

    // r13: r10 structure (5 launches) + dbuf/swizzle port into gemm role.
    prep_in<<<4608, 256, 0, stream>>>(inputs, main_h, hyper_h, hyper_k, hyper_rk,
                                      xh, mh, hh, BTh, flag);
    gemm_hyper_wt<<<12288, 256, 0, stream>>>(xh, mh, hh, BTh, zbuf, inputs,
                                             kernel_w, rec_w, dx_w, dh_w, db_w,
                                             kT, rkT, dxT, dhT, dbT);
    hyper_cell<<<2048, 256, 0, stream>>>(zbuf, hyper_c, hyper_b, d_out, ho, flag);
    mega_fused<<<dim3(64, 16), 256, 0, stream>>>(gp != 0 ? xh : xh, mh, ho, kT, rkT, dxT, dhT, dbT,
                                                 bias, dx_b, dh_b, db_b, gp, flag);
    ln_main<<<2048, 256, 0, stream>>>(gp, main_c, d_out, flag);
}